// Round 11
// baseline (916.029 us; speedup 1.0000x reference)
//
#include <hip/hip_runtime.h>
#include <cstddef>
#include <cstdint>

#define N_TOK 1024
#define D_MODEL 512
#define H_HEADS 16
#define DHEAD 32
#define DFF 2048

typedef __attribute__((ext_vector_type(8))) short short8;
typedef __attribute__((ext_vector_type(4))) float f32x4_t;

__device__ __forceinline__ float sigmoidf_(float x){ return 1.f/(1.f+__expf(-x)); }

__device__ __forceinline__ unsigned short f2bf(float f){
  union { float f; unsigned u; } v; v.f = f;
  unsigned r = (v.u + 0x7FFFu + ((v.u >> 16) & 1u)) >> 16;
  return (unsigned short)r;
}
__device__ __forceinline__ float bf_lo(unsigned u){ return __uint_as_float(u << 16); }
__device__ __forceinline__ float bf_hi(unsigned u){ return __uint_as_float(u & 0xFFFF0000u); }

// XCD-pinning swizzle (performance heuristic only; correctness does not depend on it)
__device__ __forceinline__ int swz_head(int b){ return (b & 7) + 8 * ((b >> 3) & 1); }

// ---------------- LayerNorm over rows -> bf16 out ----------------
__global__ __launch_bounds__(256) void ln_rows(const float* __restrict__ x,
                                               const float* __restrict__ w,
                                               const float* __restrict__ b,
                                               unsigned short* __restrict__ y) {
  int row = blockIdx.x;
  const float* xr = x + (size_t)row * D_MODEL;
  float s = 0.f, s2 = 0.f;
  for (int i = threadIdx.x; i < D_MODEL; i += 256) { float v = xr[i]; s += v; s2 += v*v; }
  #pragma unroll
  for (int off = 32; off; off >>= 1) { s += __shfl_down(s, off); s2 += __shfl_down(s2, off); }
  __shared__ float rs[4], rs2[4];
  int wave = threadIdx.x >> 6, lane = threadIdx.x & 63;
  if (lane == 0) { rs[wave] = s; rs2[wave] = s2; }
  __syncthreads();
  s  = rs[0] + rs[1] + rs[2] + rs[3];
  s2 = rs2[0] + rs2[1] + rs2[2] + rs2[3];
  float mean = s * (1.f / D_MODEL);
  float var  = s2 * (1.f / D_MODEL) - mean * mean;
  float r = rsqrtf(var + 1e-5f);
  unsigned short* yr = y + (size_t)row * D_MODEL;
  for (int i = threadIdx.x; i < D_MODEL; i += 256)
    yr[i] = f2bf((xr[i] - mean) * r * w[i] + b[i]);
}

// ---------------- weight conversion fp32 -> bf16 ----------------
__global__ __launch_bounds__(256) void conv_weights(const float* __restrict__ wq,
                                                    const float* __restrict__ wk,
                                                    const float* __restrict__ wv,
                                                    const float* __restrict__ wg,
                                                    const float* __restrict__ wo,
                                                    const float* __restrict__ w1,
                                                    const float* __restrict__ w3,
                                                    const float* __restrict__ w2,
                                                    unsigned short* __restrict__ dst) {
  size_t i = ((size_t)blockIdx.x * 256 + threadIdx.x) * 4;
  const float* src; size_t off;
  if      (i < 262144)  { src = wq; off = i; }
  else if (i < 524288)  { src = wk; off = i - 262144; }
  else if (i < 786432)  { src = wv; off = i - 524288; }
  else if (i < 1048576) { src = wg; off = i - 786432; }
  else if (i < 1310720) { src = wo; off = i - 1048576; }
  else if (i < 2359296) { src = w1; off = i - 1310720; }
  else if (i < 3407872) { src = w3; off = i - 2359296; }
  else                  { src = w2; off = i - 3407872; }
  float4 v = *(const float4*)&src[off];
  unsigned lo = ((unsigned)f2bf(v.y) << 16) | f2bf(v.x);
  unsigned hi = ((unsigned)f2bf(v.w) << 16) | f2bf(v.z);
  *(uint2*)&dst[i] = make_uint2(lo, hi);
}

// ---------------- bf16 MFMA GEMM 128x128: C = A @ B^T ----------------
__global__ __launch_bounds__(256) void gemm_mfma(const unsigned short* __restrict__ A,
                                                 const unsigned short* __restrict__ B,
                                                 float* __restrict__ C,
                                                 int M, int K, int Nout,
                                                 const float* __restrict__ addmat,
                                                 const float* __restrict__ maskrow) {
  __shared__ unsigned short As[128][40];
  __shared__ unsigned short Bs[128][40];
  int t = threadIdx.x;
  int m0 = blockIdx.y * 128, n0 = blockIdx.x * 128;
  int wave = t >> 6, lane = t & 63;
  int wm = (wave >> 1) * 64, wn = (wave & 1) * 64;
  int lm = lane & 15, quad = lane >> 4;
  f32x4_t zero = {0.f, 0.f, 0.f, 0.f};
  f32x4_t acc[4][4];
  #pragma unroll
  for (int i = 0; i < 4; ++i)
    #pragma unroll
    for (int j = 0; j < 4; ++j) acc[i][j] = zero;

  int sr = t >> 2, sc = (t & 3) * 8;
  for (int kk = 0; kk < K; kk += 32) {
    #pragma unroll
    for (int c = 0; c < 2; ++c) {
      int r = sr + c * 64;
      *(uint4*)&As[r][sc] = *(const uint4*)&A[(size_t)(m0 + r) * K + kk + sc];
      *(uint4*)&Bs[r][sc] = *(const uint4*)&B[(size_t)(n0 + r) * K + kk + sc];
    }
    __syncthreads();
    short8 af[4], bfr[4];
    #pragma unroll
    for (int mt = 0; mt < 4; ++mt)
      af[mt] = *(const short8*)&As[wm + mt * 16 + lm][quad * 8];
    #pragma unroll
    for (int nt = 0; nt < 4; ++nt)
      bfr[nt] = *(const short8*)&Bs[wn + nt * 16 + lm][quad * 8];
    #pragma unroll
    for (int mt = 0; mt < 4; ++mt)
      #pragma unroll
      for (int nt = 0; nt < 4; ++nt)
        acc[mt][nt] = __builtin_amdgcn_mfma_f32_16x16x32_bf16(af[mt], bfr[nt], acc[mt][nt], 0, 0, 0);
    __syncthreads();
  }
  #pragma unroll
  for (int mt = 0; mt < 4; ++mt) {
    #pragma unroll
    for (int reg = 0; reg < 4; ++reg) {
      int gm = m0 + wm + mt * 16 + quad * 4 + reg;
      float mk = maskrow ? maskrow[gm] : 0.f;
      #pragma unroll
      for (int nt = 0; nt < 4; ++nt) {
        int gn = n0 + wn + nt * 16 + lm;
        float v = acc[mt][nt][reg];
        if (addmat) v = addmat[(size_t)gm * Nout + gn] + v * mk;
        C[(size_t)gm * Nout + gn] = v;
      }
    }
  }
}

// ---------------- bf16 MFMA GEMM 64x64 ----------------
__global__ __launch_bounds__(256) void gemm_mfma64(const unsigned short* __restrict__ A,
                                                   const unsigned short* __restrict__ B,
                                                   float* __restrict__ C,
                                                   int M, int K, int Nout,
                                                   const float* __restrict__ addmat,
                                                   const float* __restrict__ maskrow) {
  __shared__ unsigned short As[64][40];
  __shared__ unsigned short Bs[64][40];
  int t = threadIdx.x;
  int m0 = blockIdx.y * 64, n0 = blockIdx.x * 64;
  int wave = t >> 6, lane = t & 63;
  int wm = (wave >> 1) * 32, wn = (wave & 1) * 32;
  int lm = lane & 15, quad = lane >> 4;
  f32x4_t zero = {0.f, 0.f, 0.f, 0.f};
  f32x4_t acc[2][2];
  #pragma unroll
  for (int i = 0; i < 2; ++i)
    #pragma unroll
    for (int j = 0; j < 2; ++j) acc[i][j] = zero;

  int sr = t >> 2, sc = (t & 3) * 8;
  for (int kk = 0; kk < K; kk += 32) {
    *(uint4*)&As[sr][sc] = *(const uint4*)&A[(size_t)(m0 + sr) * K + kk + sc];
    *(uint4*)&Bs[sr][sc] = *(const uint4*)&B[(size_t)(n0 + sr) * K + kk + sc];
    __syncthreads();
    short8 af[2], bfr[2];
    #pragma unroll
    for (int mt = 0; mt < 2; ++mt)
      af[mt] = *(const short8*)&As[wm + mt * 16 + lm][quad * 8];
    #pragma unroll
    for (int nt = 0; nt < 2; ++nt)
      bfr[nt] = *(const short8*)&Bs[wn + nt * 16 + lm][quad * 8];
    #pragma unroll
    for (int mt = 0; mt < 2; ++mt)
      #pragma unroll
      for (int nt = 0; nt < 2; ++nt)
        acc[mt][nt] = __builtin_amdgcn_mfma_f32_16x16x32_bf16(af[mt], bfr[nt], acc[mt][nt], 0, 0, 0);
    __syncthreads();
  }
  #pragma unroll
  for (int mt = 0; mt < 2; ++mt) {
    #pragma unroll
    for (int reg = 0; reg < 4; ++reg) {
      int gm = m0 + wm + mt * 16 + quad * 4 + reg;
      float mk = maskrow ? maskrow[gm] : 0.f;
      #pragma unroll
      for (int nt = 0; nt < 2; ++nt) {
        int gn = n0 + wn + nt * 16 + lm;
        float v = acc[mt][nt][reg];
        if (addmat) v = addmat[(size_t)gm * Nout + gn] + v * mk;
        C[(size_t)gm * Nout + gn] = v;
      }
    }
  }
}

// ---------------- per-head LN (no affine), Q and K regions of QKVG (ld=2048) ----------------
__global__ __launch_bounds__(256) void headln(float* __restrict__ base, int ld) {
  int g = blockIdx.x * 256 + threadIdx.x;
  int i = g & (N_TOK - 1), hh = g >> 10;    // hh 0..31
  float* p = base + (size_t)i * ld + hh * DHEAD;
  float s = 0.f, s2 = 0.f;
  #pragma unroll
  for (int k = 0; k < DHEAD; ++k) { float v = p[k]; s += v; s2 += v*v; }
  float m = s * (1.f / DHEAD);
  float var = s2 * (1.f / DHEAD) - m * m;
  float r = rsqrtf(var + 1e-5f);
  #pragma unroll
  for (int k = 0; k < DHEAD; ++k) p[k] = (p[k] - m) * r;
}

// ---------------- build W = exp(logK) via MFMA QK^T; 64x64 tile; XCD-pinned ----------------
__global__ __launch_bounds__(256) void build_W_mfma(const float* __restrict__ Q0,
                                                    const float* __restrict__ K0,
                                                    int ld,
                                                    const float* __restrict__ xres,
                                                    const int* __restrict__ bins,
                                                    const float* __restrict__ posw,
                                                    const float* __restrict__ wdl,
                                                    const float* __restrict__ epsp,
                                                    const float* __restrict__ mask,
                                                    unsigned short* __restrict__ Wm) {
  int b = blockIdx.x;                 // 4096 blocks, 256 tiles per head
  int h = swz_head(b);
  int tile = b >> 4;                  // 0..255
  int i0 = (tile >> 4) * 64, j0 = (tile & 15) * 64;
  __shared__ unsigned short Qs[64][40];
  __shared__ unsigned short Ks[64][40];
  __shared__ unsigned char  binsU[64][68];
  __shared__ unsigned short tileB[64][68];   // result in packed bf16
  __shared__ float xi0[64], xi1[64], xi2[64], xj0[64], xj1[64], xj2[64];
  __shared__ float mi_s[64], mj_s[64], poswS[68];
  int t = threadIdx.x;
  {
    int r = t >> 2, c8 = (t & 3) * 8;
    const float* qsrc = Q0 + (size_t)(i0 + r) * ld + h * DHEAD + c8;
    const float* ksrc = K0 + (size_t)(j0 + r) * ld + h * DHEAD + c8;
    float4 qa = *(const float4*)qsrc, qb = *(const float4*)(qsrc + 4);
    float4 ka = *(const float4*)ksrc, kb = *(const float4*)(ksrc + 4);
    unsigned short* qd = &Qs[r][c8];
    qd[0]=f2bf(qa.x); qd[1]=f2bf(qa.y); qd[2]=f2bf(qa.z); qd[3]=f2bf(qa.w);
    qd[4]=f2bf(qb.x); qd[5]=f2bf(qb.y); qd[6]=f2bf(qb.z); qd[7]=f2bf(qb.w);
    unsigned short* kd = &Ks[r][c8];
    kd[0]=f2bf(ka.x); kd[1]=f2bf(ka.y); kd[2]=f2bf(ka.z); kd[3]=f2bf(ka.w);
    kd[4]=f2bf(kb.x); kd[5]=f2bf(kb.y); kd[6]=f2bf(kb.z); kd[7]=f2bf(kb.w);
  }
  {
    int rb = t >> 2, cb = (t & 3) * 16;
    const int* bsrc = bins + (size_t)(i0 + rb) * N_TOK + j0 + cb;
    #pragma unroll
    for (int c = 0; c < 4; ++c) {
      int4 b4 = *(const int4*)(bsrc + c * 4);
      uchar4 u4 = make_uchar4((unsigned char)b4.x, (unsigned char)b4.y,
                              (unsigned char)b4.z, (unsigned char)b4.w);
      *(uchar4*)&binsU[rb][cb + c * 4] = u4;
    }
  }
  if (t < 64) {
    xi0[t] = xres[(i0 + t) * 3 + 0]; xi1[t] = xres[(i0 + t) * 3 + 1]; xi2[t] = xres[(i0 + t) * 3 + 2];
    xj0[t] = xres[(j0 + t) * 3 + 0]; xj1[t] = xres[(j0 + t) * 3 + 1]; xj2[t] = xres[(j0 + t) * 3 + 2];
    mi_s[t] = mask[i0 + t]; mj_s[t] = mask[j0 + t];
  }
  if (t >= 64 && t < 132) poswS[t - 64] = posw[(t - 64) * H_HEADS + h];
  __syncthreads();
  int wave = t >> 6, lane = t & 63;
  int lm = lane & 15, quad = lane >> 4;
  int wm = (wave >> 1) * 32, wn = (wave & 1) * 32;
  f32x4_t zero = {0.f, 0.f, 0.f, 0.f};
  f32x4_t acc[2][2] = {{zero, zero}, {zero, zero}};
  short8 af[2], bfr[2];
  #pragma unroll
  for (int mt = 0; mt < 2; ++mt) af[mt] = *(const short8*)&Qs[wm + mt * 16 + lm][quad * 8];
  #pragma unroll
  for (int nt = 0; nt < 2; ++nt) bfr[nt] = *(const short8*)&Ks[wn + nt * 16 + lm][quad * 8];
  #pragma unroll
  for (int mt = 0; mt < 2; ++mt)
    #pragma unroll
    for (int nt = 0; nt < 2; ++nt)
      acc[mt][nt] = __builtin_amdgcn_mfma_f32_16x16x32_bf16(af[mt], bfr[nt], acc[mt][nt], 0, 0, 0);
  float wd = sigmoidf_(wdl[h]);
  float inv_eps = 1.f / epsp[h];
  const float inv_sqrt = 0.17677669529663687f; // 1/sqrt(32)
  #pragma unroll
  for (int mt = 0; mt < 2; ++mt) {
    #pragma unroll
    for (int nt = 0; nt < 2; ++nt) {
      int col = wn + nt * 16 + lm;
      float xj0v = xj0[col], xj1v = xj1[col], xj2v = xj2[col], mj = mj_s[col];
      #pragma unroll
      for (int reg = 0; reg < 4; ++reg) {
        int row = wm + mt * 16 + quad * 4 + reg;
        float d0 = xi0[row] - xj0v, d1 = xi1[row] - xj1v, d2c = xi2[row] - xj2v;
        float d2 = d0*d0 + d1*d1 + d2c*d2c;
        float bias = poswS[binsU[row][col]];
        float logit = acc[mt][nt][reg] * inv_sqrt + bias - wd * d2 * 0.01f;
        float outv = (mi_s[row] * mj > 0.f) ? __expf(logit * inv_eps) : 0.f;
        tileB[row][col] = f2bf(outv);
      }
    }
  }
  __syncthreads();
  {
    int r = t >> 2, cb = (t & 3) * 16;
    unsigned short* dst = Wm + ((size_t)h * N_TOK + (i0 + r)) * N_TOK + j0 + cb;
    uint4 w0 = *(uint4*)&tileB[r][cb];
    uint4 w1v = *(uint4*)&tileB[r][cb + 8];
    *(uint4*)dst = w0;
    *(uint4*)(dst + 8) = w1v;
  }
}

// ---------------- build VxT: Vxt[h][48][1024] bf16 = [V^T ; x^T ; ones ; pad] ----------------
__global__ __launch_bounds__(256) void build_vxt(const float* __restrict__ QKVG_,
                                                 const float* __restrict__ xres,
                                                 unsigned short* __restrict__ Vxt) {
  int h = blockIdx.x, j0 = blockIdx.y * 64;
  __shared__ float T[48][72];
  int t = threadIdx.x;
  {
    int j = t >> 2, c8 = (t & 3) * 8;
    const float* src = QKVG_ + (size_t)(j0 + j) * 2048 + 1024 + h * DHEAD + c8;
    float4 a = *(const float4*)src, b = *(const float4*)(src + 4);
    T[c8 + 0][j] = a.x; T[c8 + 1][j] = a.y; T[c8 + 2][j] = a.z; T[c8 + 3][j] = a.w;
    T[c8 + 4][j] = b.x; T[c8 + 5][j] = b.y; T[c8 + 6][j] = b.z; T[c8 + 7][j] = b.w;
  }
  if (t < 64) {
    int j = t;
    T[32][j] = xres[(j0 + j) * 3 + 0];
    T[33][j] = xres[(j0 + j) * 3 + 1];
    T[34][j] = xres[(j0 + j) * 3 + 2];
    T[35][j] = 1.f;
    #pragma unroll
    for (int d = 36; d < 48; ++d) T[d][j] = 0.f;
  }
  __syncthreads();
  for (int task = t; task < 384; task += 256) {
    int d = task >> 3, jc = (task & 7) * 8;
    float* s = &T[d][jc];
    unsigned a0 = ((unsigned)f2bf(s[1]) << 16) | f2bf(s[0]);
    unsigned a1 = ((unsigned)f2bf(s[3]) << 16) | f2bf(s[2]);
    unsigned a2 = ((unsigned)f2bf(s[5]) << 16) | f2bf(s[4]);
    unsigned a3 = ((unsigned)f2bf(s[7]) << 16) | f2bf(s[6]);
    *(uint4*)(Vxt + ((size_t)h * 48 + d) * N_TOK + j0 + jc) = make_uint4(a0, a1, a2, a3);
  }
}

// ---------------- Sinkhorn init: log-marginals + exp warm-start + barrier zero ----------
__global__ __launch_bounds__(256) void sink_init(const float* __restrict__ mu,
                                                 const float* __restrict__ nu,
                                                 const float* __restrict__ lv0,
                                                 float* __restrict__ lmu,
                                                 float* __restrict__ lnu,
                                                 float* __restrict__ vtilde,
                                                 int* __restrict__ bar) {
  int i = blockIdx.x * 256 + threadIdx.x;   // 16384
  lmu[i] = __logf(fmaxf(mu[i], 1e-8f));
  lnu[i] = __logf(fmaxf(nu[i], 1e-8f));
  vtilde[i] = __expf(lv0[i]);
  if (i < 1024) bar[i] = 0;
}

// ---------------- per-head device-scope barrier (16 blocks arrive) ----------------
__device__ __forceinline__ void head_bar(int* cnt, int* gen, int target) {
  __syncthreads();
  if (threadIdx.x == 0) {
    __threadfence();                         // publish this block's writes
    if (atomicAdd(cnt, 1) == 15) {           // last of 16 arrivals
      atomicExch(cnt, 0);                    // reset for next barrier
      atomicAdd(gen, 1);                     // release
    } else {
      while (atomicAdd(gen, 0) < target) __builtin_amdgcn_s_sleep(1);
    }
    __threadfence();                         // acquire others' writes
  }
  __syncthreads();
}

// ---------------- persistent Sinkhorn: plain launch, per-head atomic barriers ----------
// 256 blocks x 256 thr, __launch_bounds__(256,1): 256 blocks <= 256 CUs -> co-resident.
__global__ __launch_bounds__(256, 1) void sink_persist(const unsigned short* __restrict__ Wm,
                                                       float* __restrict__ vtilde,
                                                       float* __restrict__ utilde,
                                                       const float* __restrict__ lmu,
                                                       const float* __restrict__ lnu,
                                                       float* __restrict__ out_lu,
                                                       float* __restrict__ out_lv,
                                                       const float* __restrict__ epsp,
                                                       int* __restrict__ bar) {
  int b = blockIdx.x;
  int h = swz_head(b);
  int kslot = b >> 4;                        // 0..15: block index within head
  int* cnt = bar + h * 64;                   // one cacheline per head
  int* gen = bar + h * 64 + 32;
  int t = threadIdx.x;
  int wave = t >> 6, lane = t & 63;
  int sub = lane >> 4, l16 = lane & 15;
  float fi = 1.f / (1.f + epsp[h]);          // LAM=1
  __shared__ float red[16][68];
  const unsigned short* Wh = Wm + (size_t)h * N_TOK * N_TOK;
  int j0 = kslot * 64;
  int jl = (t & 15) * 4, ig = t >> 4;
  int target = 0;

  for (int it = 0; it < 20; ++it) {
    // ---- row phase: 64 rows per block; wave does 4 rows x 4 rounds, 16 lanes/row ----
    #pragma unroll
    for (int rd = 0; rd < 4; ++rd) {
      int i = kslot * 64 + wave * 16 + rd * 4 + sub;
      const uint4* p = (const uint4*)(Wh + (size_t)i * N_TOK);
      const float4* vt4 = (const float4*)(vtilde + h * N_TOK);
      float s8[8];
      #pragma unroll
      for (int c = 0; c < 8; ++c) s8[c] = 0.f;
      #pragma unroll
      for (int q = 0; q < 8; ++q) {
        int jj = q * 128 + l16 * 8;
        uint4 u = p[jj >> 3];
        float4 va = vt4[jj >> 2];
        float4 vb = vt4[(jj >> 2) + 1];
        s8[0] += bf_lo(u.x) * va.x; s8[1] += bf_hi(u.x) * va.y;
        s8[2] += bf_lo(u.y) * va.z; s8[3] += bf_hi(u.y) * va.w;
        s8[4] += bf_lo(u.z) * vb.x; s8[5] += bf_hi(u.z) * vb.y;
        s8[6] += bf_lo(u.w) * vb.z; s8[7] += bf_hi(u.w) * vb.w;
      }
      float s = ((s8[0] + s8[1]) + (s8[2] + s8[3])) + ((s8[4] + s8[5]) + (s8[6] + s8[7]));
      #pragma unroll
      for (int off = 1; off <= 8; off <<= 1) s += __shfl_xor(s, off);
      if (l16 == 0) {
        float val = fi * (lmu[h * N_TOK + i] - __logf(fmaxf(s, 1e-35f)));
        out_lu[h * N_TOK + i] = val;
        utilde[h * N_TOK + i] = __expf(val);
      }
    }
    ++target; head_bar(cnt, gen, target);
    // ---- col phase: one 64-col tile per block, coalesced row-major reads ----
    {
      const unsigned short* base = Wh + (size_t)(ig * 64) * N_TOK + j0 + jl;
      const float* ut = utilde + h * N_TOK + ig * 64;
      float a0 = 0.f, a1 = 0.f, a2 = 0.f, a3 = 0.f;
      #pragma unroll 8
      for (int r = 0; r < 64; ++r) {
        uint2 w = *(const uint2*)(base + (size_t)r * N_TOK);
        float u = ut[r];
        a0 += bf_lo(w.x) * u; a1 += bf_hi(w.x) * u;
        a2 += bf_lo(w.y) * u; a3 += bf_hi(w.y) * u;
      }
      red[ig][jl + 0] = a0; red[ig][jl + 1] = a1;
      red[ig][jl + 2] = a2; red[ig][jl + 3] = a3;
      __syncthreads();
      if (t < 64) {
        float s = 0.f;
        #pragma unroll
        for (int g = 0; g < 16; ++g) s += red[g][t];
        int j = j0 + t;
        float val = fi * (lnu[h * N_TOK + j] - __logf(fmaxf(s, 1e-35f)));
        out_lv[h * N_TOK + j] = val;
        vtilde[h * N_TOK + j] = __expf(val);
      }
    }
    ++target; head_bar(cnt, gen, target);
  }
}

// ---------------- MFMA finalize (linear): A-frag = W * vtilde; B = Vxt; XCD-pinned -------
__global__ __launch_bounds__(256) void finalize_mfma(const unsigned short* __restrict__ Wm,
                                                     const float* __restrict__ vtilde,
                                                     const unsigned short* __restrict__ Vxt,
                                                     const float* __restrict__ G0, int ld,
                                                     const float* __restrict__ xres,
                                                     const float* __restrict__ mask,
                                                     unsigned short* __restrict__ o,
                                                     float* __restrict__ x_out,
                                                     const float* __restrict__ gamma) {
  int b = blockIdx.x;                        // 256 blocks: 16 m-tiles per head
  int h = swz_head(b);
  int mt = b >> 4;
  int t = threadIdx.x, wave = t >> 6, lane = t & 63;
  int lm = lane & 15, quad = lane >> 4;
  __shared__ float vts[N_TOK];
  ((float4*)vts)[t] = ((const float4*)(vtilde + h * N_TOK))[t];
  __syncthreads();
  int arow = mt * 64 + wave * 16 + lm;
  const unsigned short* Kr = Wm + ((size_t)h * N_TOK + arow) * N_TOK + quad * 8;
  const unsigned short* Bb = Vxt + (size_t)h * 48 * N_TOK + quad * 8;
  f32x4_t zero = {0.f, 0.f, 0.f, 0.f};
  f32x4_t acc[3] = {zero, zero, zero};
  for (int kk = 0; kk < N_TOK; kk += 32) {
    uint4 u = *(const uint4*)(Kr + kk);
    float4 la = *(const float4*)&vts[kk + quad * 8];
    float4 lb = *(const float4*)&vts[kk + quad * 8 + 4];
    float p0 = bf_lo(u.x) * la.x;
    float p1 = bf_hi(u.x) * la.y;
    float p2 = bf_lo(u.y) * la.z;
    float p3 = bf_hi(u.y) * la.w;
    float p4 = bf_lo(u.z) * lb.x;
    float p5 = bf_hi(u.z) * lb.y;
    float p6 = bf_lo(u.w) * lb.z;
    float p7 = bf_hi(u.w) * lb.w;
    union { uint4 u4; short8 s8; } pk;
    pk.u4 = make_uint4(((unsigned)f2bf(p1) << 16) | f2bf(p0),
                       ((unsigned)f2bf(p3) << 16) | f2bf(p2),
                       ((unsigned)f2bf(p5) << 16) | f2bf(p4),
                       ((unsigned)f2bf(p7) << 16) | f2bf(p6));
    short8 af = pk.s8;
    #pragma unroll
    for (int nt = 0; nt < 3; ++nt) {
      short8 bfrag = *(const short8*)(Bb + (size_t)(nt * 16 + lm) * N_TOK + kk);
      acc[nt] = __builtin_amdgcn_mfma_f32_16x16x32_bf16(af, bfrag, acc[nt], 0, 0, 0);
    }
  }
  float inv[4];
  #pragma unroll
  for (int reg = 0; reg < 4; ++reg) {
    float rsum = __shfl(acc[2][reg], (quad << 4) | 3, 64);
    inv[reg] = 1.f / fmaxf(rsum, 1e-30f);
  }
  #pragma unroll
  for (int nt = 0; nt < 2; ++nt) {
    int c = nt * 16 + lm;
    #pragma unroll
    for (int reg = 0; reg < 4; ++reg) {
      int r = mt * 64 + wave * 16 + quad * 4 + reg;
      float gv = G0[(size_t)r * ld + h * DHEAD + c];
      float ovl = acc[nt][reg] * inv[reg] * sigmoidf_(gv);
      o[(size_t)r * D_MODEL + h * DHEAD + c] = f2bf(ovl);
    }
  }
  if (lm < 3) {
    float tg = tanhf(gamma[h]) * (1.f / H_HEADS);
    #pragma unroll
    for (int reg = 0; reg < 4; ++reg) {
      int r = mt * 64 + wave * 16 + quad * 4 + reg;
      float xc = acc[2][reg] * inv[reg];
      float mi = mask[r];
      atomicAdd(&x_out[r * 3 + lm], tg * mi * (xres[r * 3 + lm] - xc));
    }
  }
}

// ---------------- silu+mul from fused ffab (1024x4096) -> bf16 (1024x2048) ----------------
__global__ __launch_bounds__(256) void silu_mul_bf(const float* __restrict__ ffab,
                                                   unsigned short* __restrict__ out, int n) {
  int i = blockIdx.x * 256 + threadIdx.x;
  if (i >= n) return;
  int row = i >> 11, col = i & 2047;
  float a = ffab[(size_t)row * 4096 + col];
  float bb = ffab[(size_t)row * 4096 + 2048 + col];
  out[i] = f2bf(a * sigmoidf_(a) * bb);
}

__global__ __launch_bounds__(256) void copyf(const float* __restrict__ src,
                                             float* __restrict__ dst, int n) {
  int i = blockIdx.x * 256 + threadIdx.x;
  if (i < n) dst[i] = src[i];
}

extern "C" void kernel_launch(void* const* d_in, const int* in_sizes, int n_in,
                              void* d_out, int out_size, void* d_ws, size_t ws_size,
                              hipStream_t stream) {
  const float* h_in  = (const float*)d_in[0];
  const float* x_res = (const float*)d_in[1];
  const float* mu    = (const float*)d_in[2];
  const float* nu    = (const float*)d_in[3];
  const float* lu0   = (const float*)d_in[4];
  const float* lv0   = (const float*)d_in[5];
  const float* mask  = (const float*)d_in[6];
  const float* lnw   = (const float*)d_in[7];
  const float* lnb   = (const float*)d_in[8];
  const float* wq    = (const float*)d_in[9];
  const float* wk    = (const float*)d_in[10];
  const float* wv    = (const float*)d_in[11];
  const float* wg    = (const float*)d_in[12];
  const float* wo    = (const float*)d_in[13];
  const float* gamma = (const float*)d_in[14];
  const float* posw  = (const float*)d_in[15];
  const float* wdl   = (const float*)d_in[16];
  const float* lnfw  = (const float*)d_in[17];
  const float* lnfb  = (const float*)d_in[18];
  const float* w1    = (const float*)d_in[19];
  const float* w3    = (const float*)d_in[20];
  const float* w2    = (const float*)d_in[21];
  const int*   bins  = (const int*)d_in[22];
  const float* eps   = (const float*)d_in[23];

  float* out    = (float*)d_out;
  float* out_h  = out;                     // 1024*512
  float* out_x  = out + 524288;            // 1024*3
  float* out_lu = out + 527360;            // 16*1024
  float* out_lv = out + 543744;            // 16*1024

  float* ws = (float*)d_ws;
  float* QKVG  = ws;                       // 1024 x 2048 (Q|K|V|G)
  float* h_mid = ws + 2097152;             // 1024 x 512
  unsigned short* U = (unsigned short*)(ws + 2621440);
  unsigned short* h_n_b  = U;              // 1024x512
  unsigned short* h2_b   = U + 524288;     // 1024x512
  unsigned short* o_b    = U + 1048576;    // 1024x512
  unsigned short* wB     = U + 1572864;    // 4456448 bf16 weights
  unsigned short* Wb   = (unsigned short*)(ws + 5636096);  // H*N*N bf16 (exp domain, 32 MB)
  unsigned short* Vxt  = Wb + (size_t)H_HEADS * N_TOK * N_TOK; // 16*48*1024 bf16
  float* vtilde = (float*)(Vxt + 786432);   // 16384 floats
  float* utilde = vtilde + 16384;
  float* lmu    = utilde + 16384;
  float* lnu    = lmu + 16384;
  unsigned short* ff_b = (unsigned short*)(lnu + 16384);  // 1024x2048 bf16 (4 MB)
  int*   barp   = (int*)(ff_b + 2097152);   // 1024 ints barrier space
  float* ffab   = (float*)Wb;               // reuse W region after finalize (16 MB)

  unsigned short* wQKVGb = wB;                 // 2048 x 512
  unsigned short* wob    = wB + 1048576;       // 512 x 512
  unsigned short* wFFb   = wB + 1310720;       // 4096 x 512
  unsigned short* w2b    = wB + 3407872;       // 512 x 2048

  dim3 b256(256);

  conv_weights<<<4352, b256, 0, stream>>>(wq, wk, wv, wg, wo, w1, w3, w2, wB);
  ln_rows<<<N_TOK, b256, 0, stream>>>(h_in, lnw, lnb, h_n_b);

  gemm_mfma<<<dim3(16, 8), b256, 0, stream>>>(h_n_b, wQKVGb, QKVG,
                                              N_TOK, D_MODEL, 2048, nullptr, nullptr);

  headln<<<128, b256, 0, stream>>>(QKVG, 2048);

  copyf<<<12, b256, 0, stream>>>(x_res, out_x, N_TOK * 3);

  build_W_mfma<<<4096, b256, 0, stream>>>(
      QKVG, QKVG + 512, 2048, x_res, bins, posw, wdl, eps, mask, Wb);
  build_vxt<<<dim3(H_HEADS, N_TOK / 64), b256, 0, stream>>>(QKVG, x_res, Vxt);

  sink_init<<<64, b256, 0, stream>>>(mu, nu, lv0, lmu, lnu, vtilde, barp);

  sink_persist<<<256, b256, 0, stream>>>(Wb, vtilde, utilde, lmu, lnu,
                                         out_lu, out_lv, eps, barp);

  finalize_mfma<<<256, b256, 0, stream>>>(
      Wb, vtilde, Vxt, QKVG + 1536, 2048, x_res, mask, o_b, out_x, gamma);

  gemm_mfma64<<<dim3(8, 16), b256, 0, stream>>>(o_b, wob, h_mid,
                                                N_TOK, D_MODEL, D_MODEL, h_in, mask);

  ln_rows<<<N_TOK, b256, 0, stream>>>(h_mid, lnfw, lnfb, h2_b);

  gemm_mfma<<<dim3(32, 8), b256, 0, stream>>>(h2_b, wFFb, ffab,
                                              N_TOK, D_MODEL, 4096, nullptr, nullptr);
  silu_mul_bf<<<(N_TOK * DFF) / 256, b256, 0, stream>>>(ffab, ff_b, N_TOK * DFF);

  gemm_mfma64<<<dim3(8, 16), b256, 0, stream>>>(ff_b, w2b, out_h,
                                                N_TOK, DFF, D_MODEL, h_mid, mask);
}

// Round 12
// 424.887 us; speedup vs baseline: 2.1559x; 2.1559x over previous
//
#include <hip/hip_runtime.h>
#include <cstddef>
#include <cstdint>

#define N_TOK 1024
#define D_MODEL 512
#define H_HEADS 16
#define DHEAD 32
#define DFF 2048

typedef __attribute__((ext_vector_type(8))) short short8;
typedef __attribute__((ext_vector_type(4))) float f32x4_t;

__device__ __forceinline__ float sigmoidf_(float x){ return 1.f/(1.f+__expf(-x)); }

__device__ __forceinline__ unsigned short f2bf(float f){
  union { float f; unsigned u; } v; v.f = f;
  unsigned r = (v.u + 0x7FFFu + ((v.u >> 16) & 1u)) >> 16;
  return (unsigned short)r;
}
__device__ __forceinline__ float bf_lo(unsigned u){ return __uint_as_float(u << 16); }
__device__ __forceinline__ float bf_hi(unsigned u){ return __uint_as_float(u & 0xFFFF0000u); }

// XCD-pinning swizzle (performance heuristic only; correctness does not depend on it)
__device__ __forceinline__ int swz_head(int b){ return (b & 7) + 8 * ((b >> 3) & 1); }

// ---------------- LayerNorm over rows -> bf16 out ----------------
__global__ __launch_bounds__(256) void ln_rows(const float* __restrict__ x,
                                               const float* __restrict__ w,
                                               const float* __restrict__ b,
                                               unsigned short* __restrict__ y) {
  int row = blockIdx.x;
  const float* xr = x + (size_t)row * D_MODEL;
  float s = 0.f, s2 = 0.f;
  for (int i = threadIdx.x; i < D_MODEL; i += 256) { float v = xr[i]; s += v; s2 += v*v; }
  #pragma unroll
  for (int off = 32; off; off >>= 1) { s += __shfl_down(s, off); s2 += __shfl_down(s2, off); }
  __shared__ float rs[4], rs2[4];
  int wave = threadIdx.x >> 6, lane = threadIdx.x & 63;
  if (lane == 0) { rs[wave] = s; rs2[wave] = s2; }
  __syncthreads();
  s  = rs[0] + rs[1] + rs[2] + rs[3];
  s2 = rs2[0] + rs2[1] + rs2[2] + rs2[3];
  float mean = s * (1.f / D_MODEL);
  float var  = s2 * (1.f / D_MODEL) - mean * mean;
  float r = rsqrtf(var + 1e-5f);
  unsigned short* yr = y + (size_t)row * D_MODEL;
  for (int i = threadIdx.x; i < D_MODEL; i += 256)
    yr[i] = f2bf((xr[i] - mean) * r * w[i] + b[i]);
}

// ---------------- weight conversion fp32 -> bf16 ----------------
__global__ __launch_bounds__(256) void conv_weights(const float* __restrict__ wq,
                                                    const float* __restrict__ wk,
                                                    const float* __restrict__ wv,
                                                    const float* __restrict__ wg,
                                                    const float* __restrict__ wo,
                                                    const float* __restrict__ w1,
                                                    const float* __restrict__ w3,
                                                    const float* __restrict__ w2,
                                                    unsigned short* __restrict__ dst) {
  size_t i = ((size_t)blockIdx.x * 256 + threadIdx.x) * 4;
  const float* src; size_t off;
  if      (i < 262144)  { src = wq; off = i; }
  else if (i < 524288)  { src = wk; off = i - 262144; }
  else if (i < 786432)  { src = wv; off = i - 524288; }
  else if (i < 1048576) { src = wg; off = i - 786432; }
  else if (i < 1310720) { src = wo; off = i - 1048576; }
  else if (i < 2359296) { src = w1; off = i - 1310720; }
  else if (i < 3407872) { src = w3; off = i - 2359296; }
  else                  { src = w2; off = i - 3407872; }
  float4 v = *(const float4*)&src[off];
  unsigned lo = ((unsigned)f2bf(v.y) << 16) | f2bf(v.x);
  unsigned hi = ((unsigned)f2bf(v.w) << 16) | f2bf(v.z);
  *(uint2*)&dst[i] = make_uint2(lo, hi);
}

// ---------------- bf16 MFMA GEMM 128x128: C = A @ B^T ----------------
__global__ __launch_bounds__(256) void gemm_mfma(const unsigned short* __restrict__ A,
                                                 const unsigned short* __restrict__ B,
                                                 float* __restrict__ C,
                                                 int M, int K, int Nout,
                                                 const float* __restrict__ addmat,
                                                 const float* __restrict__ maskrow) {
  __shared__ unsigned short As[128][40];
  __shared__ unsigned short Bs[128][40];
  int t = threadIdx.x;
  int m0 = blockIdx.y * 128, n0 = blockIdx.x * 128;
  int wave = t >> 6, lane = t & 63;
  int wm = (wave >> 1) * 64, wn = (wave & 1) * 64;
  int lm = lane & 15, quad = lane >> 4;
  f32x4_t zero = {0.f, 0.f, 0.f, 0.f};
  f32x4_t acc[4][4];
  #pragma unroll
  for (int i = 0; i < 4; ++i)
    #pragma unroll
    for (int j = 0; j < 4; ++j) acc[i][j] = zero;

  int sr = t >> 2, sc = (t & 3) * 8;
  for (int kk = 0; kk < K; kk += 32) {
    #pragma unroll
    for (int c = 0; c < 2; ++c) {
      int r = sr + c * 64;
      *(uint4*)&As[r][sc] = *(const uint4*)&A[(size_t)(m0 + r) * K + kk + sc];
      *(uint4*)&Bs[r][sc] = *(const uint4*)&B[(size_t)(n0 + r) * K + kk + sc];
    }
    __syncthreads();
    short8 af[4], bfr[4];
    #pragma unroll
    for (int mt = 0; mt < 4; ++mt)
      af[mt] = *(const short8*)&As[wm + mt * 16 + lm][quad * 8];
    #pragma unroll
    for (int nt = 0; nt < 4; ++nt)
      bfr[nt] = *(const short8*)&Bs[wn + nt * 16 + lm][quad * 8];
    #pragma unroll
    for (int mt = 0; mt < 4; ++mt)
      #pragma unroll
      for (int nt = 0; nt < 4; ++nt)
        acc[mt][nt] = __builtin_amdgcn_mfma_f32_16x16x32_bf16(af[mt], bfr[nt], acc[mt][nt], 0, 0, 0);
    __syncthreads();
  }
  #pragma unroll
  for (int mt = 0; mt < 4; ++mt) {
    #pragma unroll
    for (int reg = 0; reg < 4; ++reg) {
      int gm = m0 + wm + mt * 16 + quad * 4 + reg;
      float mk = maskrow ? maskrow[gm] : 0.f;
      #pragma unroll
      for (int nt = 0; nt < 4; ++nt) {
        int gn = n0 + wn + nt * 16 + lm;
        float v = acc[mt][nt][reg];
        if (addmat) v = addmat[(size_t)gm * Nout + gn] + v * mk;
        C[(size_t)gm * Nout + gn] = v;
      }
    }
  }
}

// ---------------- bf16 MFMA GEMM 64x64 ----------------
__global__ __launch_bounds__(256) void gemm_mfma64(const unsigned short* __restrict__ A,
                                                   const unsigned short* __restrict__ B,
                                                   float* __restrict__ C,
                                                   int M, int K, int Nout,
                                                   const float* __restrict__ addmat,
                                                   const float* __restrict__ maskrow) {
  __shared__ unsigned short As[64][40];
  __shared__ unsigned short Bs[64][40];
  int t = threadIdx.x;
  int m0 = blockIdx.y * 64, n0 = blockIdx.x * 64;
  int wave = t >> 6, lane = t & 63;
  int wm = (wave >> 1) * 32, wn = (wave & 1) * 32;
  int lm = lane & 15, quad = lane >> 4;
  f32x4_t zero = {0.f, 0.f, 0.f, 0.f};
  f32x4_t acc[2][2];
  #pragma unroll
  for (int i = 0; i < 2; ++i)
    #pragma unroll
    for (int j = 0; j < 2; ++j) acc[i][j] = zero;

  int sr = t >> 2, sc = (t & 3) * 8;
  for (int kk = 0; kk < K; kk += 32) {
    *(uint4*)&As[sr][sc] = *(const uint4*)&A[(size_t)(m0 + sr) * K + kk + sc];
    *(uint4*)&Bs[sr][sc] = *(const uint4*)&B[(size_t)(n0 + sr) * K + kk + sc];
    __syncthreads();
    short8 af[2], bfr[2];
    #pragma unroll
    for (int mt = 0; mt < 2; ++mt)
      af[mt] = *(const short8*)&As[wm + mt * 16 + lm][quad * 8];
    #pragma unroll
    for (int nt = 0; nt < 2; ++nt)
      bfr[nt] = *(const short8*)&Bs[wn + nt * 16 + lm][quad * 8];
    #pragma unroll
    for (int mt = 0; mt < 2; ++mt)
      #pragma unroll
      for (int nt = 0; nt < 2; ++nt)
        acc[mt][nt] = __builtin_amdgcn_mfma_f32_16x16x32_bf16(af[mt], bfr[nt], acc[mt][nt], 0, 0, 0);
    __syncthreads();
  }
  #pragma unroll
  for (int mt = 0; mt < 2; ++mt) {
    #pragma unroll
    for (int reg = 0; reg < 4; ++reg) {
      int gm = m0 + wm + mt * 16 + quad * 4 + reg;
      float mk = maskrow ? maskrow[gm] : 0.f;
      #pragma unroll
      for (int nt = 0; nt < 2; ++nt) {
        int gn = n0 + wn + nt * 16 + lm;
        float v = acc[mt][nt][reg];
        if (addmat) v = addmat[(size_t)gm * Nout + gn] + v * mk;
        C[(size_t)gm * Nout + gn] = v;
      }
    }
  }
}

// ---------------- per-head LN (no affine), Q and K regions of QKVG (ld=2048) ----------------
__global__ __launch_bounds__(256) void headln(float* __restrict__ base, int ld) {
  int g = blockIdx.x * 256 + threadIdx.x;
  int i = g & (N_TOK - 1), hh = g >> 10;    // hh 0..31
  float* p = base + (size_t)i * ld + hh * DHEAD;
  float s = 0.f, s2 = 0.f;
  #pragma unroll
  for (int k = 0; k < DHEAD; ++k) { float v = p[k]; s += v; s2 += v*v; }
  float m = s * (1.f / DHEAD);
  float var = s2 * (1.f / DHEAD) - m * m;
  float r = rsqrtf(var + 1e-5f);
  #pragma unroll
  for (int k = 0; k < DHEAD; ++k) p[k] = (p[k] - m) * r;
}

// ---------------- build W = exp(logK) via MFMA QK^T; 64x64 tile; XCD-pinned ----------------
__global__ __launch_bounds__(256) void build_W_mfma(const float* __restrict__ Q0,
                                                    const float* __restrict__ K0,
                                                    int ld,
                                                    const float* __restrict__ xres,
                                                    const int* __restrict__ bins,
                                                    const float* __restrict__ posw,
                                                    const float* __restrict__ wdl,
                                                    const float* __restrict__ epsp,
                                                    const float* __restrict__ mask,
                                                    unsigned short* __restrict__ Wm) {
  int b = blockIdx.x;                 // 4096 blocks, 256 tiles per head
  int h = swz_head(b);
  int tile = b >> 4;                  // 0..255
  int i0 = (tile >> 4) * 64, j0 = (tile & 15) * 64;
  __shared__ unsigned short Qs[64][40];
  __shared__ unsigned short Ks[64][40];
  __shared__ unsigned char  binsU[64][68];
  __shared__ unsigned short tileB[64][68];   // result in packed bf16
  __shared__ float xi0[64], xi1[64], xi2[64], xj0[64], xj1[64], xj2[64];
  __shared__ float mi_s[64], mj_s[64], poswS[68];
  int t = threadIdx.x;
  {
    int r = t >> 2, c8 = (t & 3) * 8;
    const float* qsrc = Q0 + (size_t)(i0 + r) * ld + h * DHEAD + c8;
    const float* ksrc = K0 + (size_t)(j0 + r) * ld + h * DHEAD + c8;
    float4 qa = *(const float4*)qsrc, qb = *(const float4*)(qsrc + 4);
    float4 ka = *(const float4*)ksrc, kb = *(const float4*)(ksrc + 4);
    unsigned short* qd = &Qs[r][c8];
    qd[0]=f2bf(qa.x); qd[1]=f2bf(qa.y); qd[2]=f2bf(qa.z); qd[3]=f2bf(qa.w);
    qd[4]=f2bf(qb.x); qd[5]=f2bf(qb.y); qd[6]=f2bf(qb.z); qd[7]=f2bf(qb.w);
    unsigned short* kd = &Ks[r][c8];
    kd[0]=f2bf(ka.x); kd[1]=f2bf(ka.y); kd[2]=f2bf(ka.z); kd[3]=f2bf(ka.w);
    kd[4]=f2bf(kb.x); kd[5]=f2bf(kb.y); kd[6]=f2bf(kb.z); kd[7]=f2bf(kb.w);
  }
  {
    int rb = t >> 2, cb = (t & 3) * 16;
    const int* bsrc = bins + (size_t)(i0 + rb) * N_TOK + j0 + cb;
    #pragma unroll
    for (int c = 0; c < 4; ++c) {
      int4 b4 = *(const int4*)(bsrc + c * 4);
      uchar4 u4 = make_uchar4((unsigned char)b4.x, (unsigned char)b4.y,
                              (unsigned char)b4.z, (unsigned char)b4.w);
      *(uchar4*)&binsU[rb][cb + c * 4] = u4;
    }
  }
  if (t < 64) {
    xi0[t] = xres[(i0 + t) * 3 + 0]; xi1[t] = xres[(i0 + t) * 3 + 1]; xi2[t] = xres[(i0 + t) * 3 + 2];
    xj0[t] = xres[(j0 + t) * 3 + 0]; xj1[t] = xres[(j0 + t) * 3 + 1]; xj2[t] = xres[(j0 + t) * 3 + 2];
    mi_s[t] = mask[i0 + t]; mj_s[t] = mask[j0 + t];
  }
  if (t >= 64 && t < 132) poswS[t - 64] = posw[(t - 64) * H_HEADS + h];
  __syncthreads();
  int wave = t >> 6, lane = t & 63;
  int lm = lane & 15, quad = lane >> 4;
  int wm = (wave >> 1) * 32, wn = (wave & 1) * 32;
  f32x4_t zero = {0.f, 0.f, 0.f, 0.f};
  f32x4_t acc[2][2] = {{zero, zero}, {zero, zero}};
  short8 af[2], bfr[2];
  #pragma unroll
  for (int mt = 0; mt < 2; ++mt) af[mt] = *(const short8*)&Qs[wm + mt * 16 + lm][quad * 8];
  #pragma unroll
  for (int nt = 0; nt < 2; ++nt) bfr[nt] = *(const short8*)&Ks[wn + nt * 16 + lm][quad * 8];
  #pragma unroll
  for (int mt = 0; mt < 2; ++mt)
    #pragma unroll
    for (int nt = 0; nt < 2; ++nt)
      acc[mt][nt] = __builtin_amdgcn_mfma_f32_16x16x32_bf16(af[mt], bfr[nt], acc[mt][nt], 0, 0, 0);
  float wd = sigmoidf_(wdl[h]);
  float inv_eps = 1.f / epsp[h];
  const float inv_sqrt = 0.17677669529663687f; // 1/sqrt(32)
  #pragma unroll
  for (int mt = 0; mt < 2; ++mt) {
    #pragma unroll
    for (int nt = 0; nt < 2; ++nt) {
      int col = wn + nt * 16 + lm;
      float xj0v = xj0[col], xj1v = xj1[col], xj2v = xj2[col], mj = mj_s[col];
      #pragma unroll
      for (int reg = 0; reg < 4; ++reg) {
        int row = wm + mt * 16 + quad * 4 + reg;
        float d0 = xi0[row] - xj0v, d1 = xi1[row] - xj1v, d2c = xi2[row] - xj2v;
        float d2 = d0*d0 + d1*d1 + d2c*d2c;
        float bias = poswS[binsU[row][col]];
        float logit = acc[mt][nt][reg] * inv_sqrt + bias - wd * d2 * 0.01f;
        float outv = (mi_s[row] * mj > 0.f) ? __expf(logit * inv_eps) : 0.f;
        tileB[row][col] = f2bf(outv);
      }
    }
  }
  __syncthreads();
  {
    int r = t >> 2, cb = (t & 3) * 16;
    unsigned short* dst = Wm + ((size_t)h * N_TOK + (i0 + r)) * N_TOK + j0 + cb;
    uint4 w0 = *(uint4*)&tileB[r][cb];
    uint4 w1v = *(uint4*)&tileB[r][cb + 8];
    *(uint4*)dst = w0;
    *(uint4*)(dst + 8) = w1v;
  }
}

// ---------------- build VxT: Vxt[h][48][1024] bf16 = [V^T ; x^T ; ones ; pad] ----------------
__global__ __launch_bounds__(256) void build_vxt(const float* __restrict__ QKVG_,
                                                 const float* __restrict__ xres,
                                                 unsigned short* __restrict__ Vxt) {
  int h = blockIdx.x, j0 = blockIdx.y * 64;
  __shared__ float T[48][72];
  int t = threadIdx.x;
  {
    int j = t >> 2, c8 = (t & 3) * 8;
    const float* src = QKVG_ + (size_t)(j0 + j) * 2048 + 1024 + h * DHEAD + c8;
    float4 a = *(const float4*)src, b = *(const float4*)(src + 4);
    T[c8 + 0][j] = a.x; T[c8 + 1][j] = a.y; T[c8 + 2][j] = a.z; T[c8 + 3][j] = a.w;
    T[c8 + 4][j] = b.x; T[c8 + 5][j] = b.y; T[c8 + 6][j] = b.z; T[c8 + 7][j] = b.w;
  }
  if (t < 64) {
    int j = t;
    T[32][j] = xres[(j0 + j) * 3 + 0];
    T[33][j] = xres[(j0 + j) * 3 + 1];
    T[34][j] = xres[(j0 + j) * 3 + 2];
    T[35][j] = 1.f;
    #pragma unroll
    for (int d = 36; d < 48; ++d) T[d][j] = 0.f;
  }
  __syncthreads();
  for (int task = t; task < 384; task += 256) {
    int d = task >> 3, jc = (task & 7) * 8;
    float* s = &T[d][jc];
    unsigned a0 = ((unsigned)f2bf(s[1]) << 16) | f2bf(s[0]);
    unsigned a1 = ((unsigned)f2bf(s[3]) << 16) | f2bf(s[2]);
    unsigned a2 = ((unsigned)f2bf(s[5]) << 16) | f2bf(s[4]);
    unsigned a3 = ((unsigned)f2bf(s[7]) << 16) | f2bf(s[6]);
    *(uint4*)(Vxt + ((size_t)h * 48 + d) * N_TOK + j0 + jc) = make_uint4(a0, a1, a2, a3);
  }
}

// ---------------- Sinkhorn init: log-marginals + exp warm-start ----------------
__global__ __launch_bounds__(256) void sink_init(const float* __restrict__ mu,
                                                 const float* __restrict__ nu,
                                                 const float* __restrict__ lv0,
                                                 float* __restrict__ lmu,
                                                 float* __restrict__ lnu,
                                                 float* __restrict__ vtilde) {
  int i = blockIdx.x * 256 + threadIdx.x;   // 16384
  lmu[i] = __logf(fmaxf(mu[i], 1e-8f));
  lnu[i] = __logf(fmaxf(nu[i], 1e-8f));
  vtilde[i] = __expf(lv0[i]);
}

// ---------------- Sinkhorn row pass it=0 (reads global vtilde), XCD-pinned ----------------
__global__ __launch_bounds__(256) void sink_row(const unsigned short* __restrict__ Wm,
                                                const float* __restrict__ vtilde,
                                                const float* __restrict__ lmu,
                                                float* __restrict__ outlog,
                                                float* __restrict__ outexp,
                                                const float* __restrict__ epsp) {
  int b = blockIdx.x;                        // 1024 blocks, 64 per head
  int h = swz_head(b);
  int grp = b >> 4;                          // 0..63 (16 rows each)
  int t = threadIdx.x;
  int wave = t >> 6, lane = t & 63;
  int sub = lane >> 4, l16 = lane & 15;      // 4 rows per wave, 16 lanes per row
  int i = grp * 16 + wave * 4 + sub;         // row within head
  const uint4* p = (const uint4*)(Wm + ((size_t)h * N_TOK + i) * N_TOK);
  const float4* vt = (const float4*)(vtilde + h * N_TOK);
  float s8[8];
  #pragma unroll
  for (int c = 0; c < 8; ++c) s8[c] = 0.f;
  #pragma unroll
  for (int it = 0; it < 8; ++it) {
    int j0 = it * 128 + l16 * 8;
    uint4 u = p[j0 >> 3];
    float4 va = vt[j0 >> 2];
    float4 vb = vt[(j0 >> 2) + 1];
    s8[0] += bf_lo(u.x) * va.x; s8[1] += bf_hi(u.x) * va.y;
    s8[2] += bf_lo(u.y) * va.z; s8[3] += bf_hi(u.y) * va.w;
    s8[4] += bf_lo(u.z) * vb.x; s8[5] += bf_hi(u.z) * vb.y;
    s8[6] += bf_lo(u.w) * vb.z; s8[7] += bf_hi(u.w) * vb.w;
  }
  float s = ((s8[0] + s8[1]) + (s8[2] + s8[3])) + ((s8[4] + s8[5]) + (s8[6] + s8[7]));
  #pragma unroll
  for (int off = 1; off <= 8; off <<= 1) s += __shfl_xor(s, off);
  if (l16 == 0) {
    float fi = 1.f / (1.f + epsp[h]);        // LAM=1
    float val = fi * (lmu[h * N_TOK + i] - __logf(fmaxf(s, 1e-35f)));
    outlog[h * N_TOK + i] = val;
    outexp[h * N_TOK + i] = __expf(val);
  }
}

// ---------------- Sinkhorn row pass it>=1: reduces col partials -> LDS vt ----------------
__global__ __launch_bounds__(256) void sink_row2(const unsigned short* __restrict__ Wm,
                                                 const float* __restrict__ part,
                                                 const float* __restrict__ lnu,
                                                 const float* __restrict__ lmu,
                                                 float* __restrict__ outlog,
                                                 float* __restrict__ outexp,
                                                 const float* __restrict__ epsp) {
  __shared__ float vt_lds[N_TOK];
  int b = blockIdx.x;                        // 1024 blocks, 64 per head
  int h = swz_head(b);
  int grp = b >> 4;
  int t = threadIdx.x;
  float fi = 1.f / (1.f + epsp[h]);
  // preamble: vt[j] = exp(fi*(lnu[j] - log(sum of 4 partials)))
  {
    int j = t * 4;
    float4 p0 = *(const float4*)(part + 0 * 16384 + h * N_TOK + j);
    float4 p1 = *(const float4*)(part + 1 * 16384 + h * N_TOK + j);
    float4 p2 = *(const float4*)(part + 2 * 16384 + h * N_TOK + j);
    float4 p3 = *(const float4*)(part + 3 * 16384 + h * N_TOK + j);
    float4 ln4 = *(const float4*)(lnu + h * N_TOK + j);
    float s0 = (p0.x + p1.x) + (p2.x + p3.x);
    float s1 = (p0.y + p1.y) + (p2.y + p3.y);
    float s2 = (p0.z + p1.z) + (p2.z + p3.z);
    float s3 = (p0.w + p1.w) + (p2.w + p3.w);
    vt_lds[j + 0] = __expf(fi * (ln4.x - __logf(fmaxf(s0, 1e-35f))));
    vt_lds[j + 1] = __expf(fi * (ln4.y - __logf(fmaxf(s1, 1e-35f))));
    vt_lds[j + 2] = __expf(fi * (ln4.z - __logf(fmaxf(s2, 1e-35f))));
    vt_lds[j + 3] = __expf(fi * (ln4.w - __logf(fmaxf(s3, 1e-35f))));
  }
  __syncthreads();
  int wave = t >> 6, lane = t & 63;
  int sub = lane >> 4, l16 = lane & 15;
  int i = grp * 16 + wave * 4 + sub;
  const uint4* p = (const uint4*)(Wm + ((size_t)h * N_TOK + i) * N_TOK);
  float s8[8];
  #pragma unroll
  for (int c = 0; c < 8; ++c) s8[c] = 0.f;
  #pragma unroll
  for (int it = 0; it < 8; ++it) {
    int j0 = it * 128 + l16 * 8;
    uint4 u = p[j0 >> 3];
    float4 va = *(const float4*)&vt_lds[j0];
    float4 vb = *(const float4*)&vt_lds[j0 + 4];
    s8[0] += bf_lo(u.x) * va.x; s8[1] += bf_hi(u.x) * va.y;
    s8[2] += bf_lo(u.y) * va.z; s8[3] += bf_hi(u.y) * va.w;
    s8[4] += bf_lo(u.z) * vb.x; s8[5] += bf_hi(u.z) * vb.y;
    s8[6] += bf_lo(u.w) * vb.z; s8[7] += bf_hi(u.w) * vb.w;
  }
  float s = ((s8[0] + s8[1]) + (s8[2] + s8[3])) + ((s8[4] + s8[5]) + (s8[6] + s8[7]));
  #pragma unroll
  for (int off = 1; off <= 8; off <<= 1) s += __shfl_xor(s, off);
  if (l16 == 0) {
    float val = fi * (lmu[h * N_TOK + i] - __logf(fmaxf(s, 1e-35f)));
    outlog[h * N_TOK + i] = val;
    outexp[h * N_TOK + i] = __expf(val);
  }
}

// ---------------- Sinkhorn col pass -> 4 partial arrays (1024 blocks), XCD-pinned --------
// block (h, chunk c, col-tile jt): partial_j = Sum_{i in chunk} W[i,j] * utilde[i]
__global__ __launch_bounds__(256) void sink_colp(const unsigned short* __restrict__ Wm,
                                                 const float* __restrict__ utilde,
                                                 float* __restrict__ part) {
  int b = blockIdx.x;                        // 1024 blocks
  int h = swz_head(b);
  int c = (b >> 4) & 3;                      // row chunk 0..3 (256 rows)
  int jt = (b >> 6) & 15;                    // col tile 0..15
  int j0 = jt * 64;
  int t = threadIdx.x;
  int jl = (t & 15) * 4;
  int ig = t >> 4;                           // 16 i-groups of 16 rows
  int r0 = c * 256 + ig * 16;
  const unsigned short* base = Wm + ((size_t)h * N_TOK + r0) * N_TOK + j0 + jl;
  const float* ut = utilde + h * N_TOK + r0;
  float a0 = 0.f, a1 = 0.f, a2 = 0.f, a3 = 0.f;
  #pragma unroll
  for (int r = 0; r < 16; ++r) {
    uint2 w = *(const uint2*)(base + (size_t)r * N_TOK);
    float u = ut[r];
    a0 += bf_lo(w.x) * u; a1 += bf_hi(w.x) * u;
    a2 += bf_lo(w.y) * u; a3 += bf_hi(w.y) * u;
  }
  __shared__ float red[16][68];
  red[ig][jl + 0] = a0; red[ig][jl + 1] = a1;
  red[ig][jl + 2] = a2; red[ig][jl + 3] = a3;
  __syncthreads();
  if (t < 64) {
    float s = 0.f;
    #pragma unroll
    for (int g = 0; g < 16; ++g) s += red[g][t];
    part[c * 16384 + h * N_TOK + j0 + t] = s;
  }
}

// ---------------- Sinkhorn finish: last partials -> final out_lv + vtilde ----------------
__global__ __launch_bounds__(256) void sink_fin(const float* __restrict__ part,
                                                const float* __restrict__ lnu,
                                                float* __restrict__ out_lv,
                                                float* __restrict__ vtilde,
                                                const float* __restrict__ epsp) {
  int h = blockIdx.x;
  int t = threadIdx.x;
  float fi = 1.f / (1.f + epsp[h]);
  int j = t * 4;
  float4 p0 = *(const float4*)(part + 0 * 16384 + h * N_TOK + j);
  float4 p1 = *(const float4*)(part + 1 * 16384 + h * N_TOK + j);
  float4 p2 = *(const float4*)(part + 2 * 16384 + h * N_TOK + j);
  float4 p3 = *(const float4*)(part + 3 * 16384 + h * N_TOK + j);
  float4 ln4 = *(const float4*)(lnu + h * N_TOK + j);
  float sv[4];
  sv[0] = (p0.x + p1.x) + (p2.x + p3.x);
  sv[1] = (p0.y + p1.y) + (p2.y + p3.y);
  sv[2] = (p0.z + p1.z) + (p2.z + p3.z);
  sv[3] = (p0.w + p1.w) + (p2.w + p3.w);
  float ln_[4] = {ln4.x, ln4.y, ln4.z, ln4.w};
  #pragma unroll
  for (int k = 0; k < 4; ++k) {
    float val = fi * (ln_[k] - __logf(fmaxf(sv[k], 1e-35f)));
    out_lv[h * N_TOK + j + k] = val;
    vtilde[h * N_TOK + j + k] = __expf(val);
  }
}

// ---------------- MFMA finalize (linear): A-frag = W * vtilde; B = Vxt; XCD-pinned -------
__global__ __launch_bounds__(256) void finalize_mfma(const unsigned short* __restrict__ Wm,
                                                     const float* __restrict__ vtilde,
                                                     const unsigned short* __restrict__ Vxt,
                                                     const float* __restrict__ G0, int ld,
                                                     const float* __restrict__ xres,
                                                     const float* __restrict__ mask,
                                                     unsigned short* __restrict__ o,
                                                     float* __restrict__ x_out,
                                                     const float* __restrict__ gamma) {
  int b = blockIdx.x;                        // 256 blocks: 16 m-tiles per head
  int h = swz_head(b);
  int mt = b >> 4;
  int t = threadIdx.x, wave = t >> 6, lane = t & 63;
  int lm = lane & 15, quad = lane >> 4;
  __shared__ float vts[N_TOK];
  ((float4*)vts)[t] = ((const float4*)(vtilde + h * N_TOK))[t];
  __syncthreads();
  int arow = mt * 64 + wave * 16 + lm;
  const unsigned short* Kr = Wm + ((size_t)h * N_TOK + arow) * N_TOK + quad * 8;
  const unsigned short* Bb = Vxt + (size_t)h * 48 * N_TOK + quad * 8;
  f32x4_t zero = {0.f, 0.f, 0.f, 0.f};
  f32x4_t acc[3] = {zero, zero, zero};
  for (int kk = 0; kk < N_TOK; kk += 32) {
    uint4 u = *(const uint4*)(Kr + kk);
    float4 la = *(const float4*)&vts[kk + quad * 8];
    float4 lb = *(const float4*)&vts[kk + quad * 8 + 4];
    float p0 = bf_lo(u.x) * la.x;
    float p1 = bf_hi(u.x) * la.y;
    float p2 = bf_lo(u.y) * la.z;
    float p3 = bf_hi(u.y) * la.w;
    float p4 = bf_lo(u.z) * lb.x;
    float p5 = bf_hi(u.z) * lb.y;
    float p6 = bf_lo(u.w) * lb.z;
    float p7 = bf_hi(u.w) * lb.w;
    union { uint4 u4; short8 s8; } pk;
    pk.u4 = make_uint4(((unsigned)f2bf(p1) << 16) | f2bf(p0),
                       ((unsigned)f2bf(p3) << 16) | f2bf(p2),
                       ((unsigned)f2bf(p5) << 16) | f2bf(p4),
                       ((unsigned)f2bf(p7) << 16) | f2bf(p6));
    short8 af = pk.s8;
    #pragma unroll
    for (int nt = 0; nt < 3; ++nt) {
      short8 bfrag = *(const short8*)(Bb + (size_t)(nt * 16 + lm) * N_TOK + kk);
      acc[nt] = __builtin_amdgcn_mfma_f32_16x16x32_bf16(af, bfrag, acc[nt], 0, 0, 0);
    }
  }
  float inv[4];
  #pragma unroll
  for (int reg = 0; reg < 4; ++reg) {
    float rsum = __shfl(acc[2][reg], (quad << 4) | 3, 64);
    inv[reg] = 1.f / fmaxf(rsum, 1e-30f);
  }
  #pragma unroll
  for (int nt = 0; nt < 2; ++nt) {
    int c = nt * 16 + lm;
    #pragma unroll
    for (int reg = 0; reg < 4; ++reg) {
      int r = mt * 64 + wave * 16 + quad * 4 + reg;
      float gv = G0[(size_t)r * ld + h * DHEAD + c];
      float ovl = acc[nt][reg] * inv[reg] * sigmoidf_(gv);
      o[(size_t)r * D_MODEL + h * DHEAD + c] = f2bf(ovl);
    }
  }
  if (lm < 3) {
    float tg = tanhf(gamma[h]) * (1.f / H_HEADS);
    #pragma unroll
    for (int reg = 0; reg < 4; ++reg) {
      int r = mt * 64 + wave * 16 + quad * 4 + reg;
      float xc = acc[2][reg] * inv[reg];
      float mi = mask[r];
      atomicAdd(&x_out[r * 3 + lm], tg * mi * (xres[r * 3 + lm] - xc));
    }
  }
}

// ---------------- silu+mul from fused ffab (1024x4096) -> bf16 (1024x2048) ----------------
__global__ __launch_bounds__(256) void silu_mul_bf(const float* __restrict__ ffab,
                                                   unsigned short* __restrict__ out, int n) {
  int i = blockIdx.x * 256 + threadIdx.x;
  if (i >= n) return;
  int row = i >> 11, col = i & 2047;
  float a = ffab[(size_t)row * 4096 + col];
  float bb = ffab[(size_t)row * 4096 + 2048 + col];
  out[i] = f2bf(a * sigmoidf_(a) * bb);
}

__global__ __launch_bounds__(256) void copyf(const float* __restrict__ src,
                                             float* __restrict__ dst, int n) {
  int i = blockIdx.x * 256 + threadIdx.x;
  if (i < n) dst[i] = src[i];
}

extern "C" void kernel_launch(void* const* d_in, const int* in_sizes, int n_in,
                              void* d_out, int out_size, void* d_ws, size_t ws_size,
                              hipStream_t stream) {
  const float* h_in  = (const float*)d_in[0];
  const float* x_res = (const float*)d_in[1];
  const float* mu    = (const float*)d_in[2];
  const float* nu    = (const float*)d_in[3];
  const float* lu0   = (const float*)d_in[4];
  const float* lv0   = (const float*)d_in[5];
  const float* mask  = (const float*)d_in[6];
  const float* lnw   = (const float*)d_in[7];
  const float* lnb   = (const float*)d_in[8];
  const float* wq    = (const float*)d_in[9];
  const float* wk    = (const float*)d_in[10];
  const float* wv    = (const float*)d_in[11];
  const float* wg    = (const float*)d_in[12];
  const float* wo    = (const float*)d_in[13];
  const float* gamma = (const float*)d_in[14];
  const float* posw  = (const float*)d_in[15];
  const float* wdl   = (const float*)d_in[16];
  const float* lnfw  = (const float*)d_in[17];
  const float* lnfb  = (const float*)d_in[18];
  const float* w1    = (const float*)d_in[19];
  const float* w3    = (const float*)d_in[20];
  const float* w2    = (const float*)d_in[21];
  const int*   bins  = (const int*)d_in[22];
  const float* eps   = (const float*)d_in[23];

  float* out    = (float*)d_out;
  float* out_h  = out;                     // 1024*512
  float* out_x  = out + 524288;            // 1024*3
  float* out_lu = out + 527360;            // 16*1024
  float* out_lv = out + 543744;            // 16*1024

  float* ws = (float*)d_ws;
  float* QKVG  = ws;                       // 1024 x 2048 (Q|K|V|G)
  float* h_mid = ws + 2097152;             // 1024 x 512
  unsigned short* U = (unsigned short*)(ws + 2621440);
  unsigned short* h_n_b  = U;              // 1024x512
  unsigned short* h2_b   = U + 524288;     // 1024x512
  unsigned short* o_b    = U + 1048576;    // 1024x512
  unsigned short* wB     = U + 1572864;    // 4456448 bf16 weights
  unsigned short* Wb   = (unsigned short*)(ws + 5636096);  // H*N*N bf16 (exp domain, 32 MB)
  unsigned short* Vxt  = Wb + (size_t)H_HEADS * N_TOK * N_TOK; // 16*48*1024 bf16
  float* vtilde = (float*)(Vxt + 786432);   // 16384 floats
  float* utilde = vtilde + 16384;
  float* lmu    = utilde + 16384;
  float* lnu    = lmu + 16384;
  float* part   = lnu + 16384;              // 4 x 16384 floats (col partials)
  unsigned short* ff_b = (unsigned short*)(part + 65536);  // 1024x2048 bf16 (4 MB)
  float* ffab   = (float*)Wb;               // reuse W region after finalize (16 MB)

  unsigned short* wQKVGb = wB;                 // 2048 x 512
  unsigned short* wob    = wB + 1048576;       // 512 x 512
  unsigned short* wFFb   = wB + 1310720;       // 4096 x 512
  unsigned short* w2b    = wB + 3407872;       // 512 x 2048

  dim3 b256(256);

  conv_weights<<<4352, b256, 0, stream>>>(wq, wk, wv, wg, wo, w1, w3, w2, wB);
  ln_rows<<<N_TOK, b256, 0, stream>>>(h_in, lnw, lnb, h_n_b);

  gemm_mfma<<<dim3(16, 8), b256, 0, stream>>>(h_n_b, wQKVGb, QKVG,
                                              N_TOK, D_MODEL, 2048, nullptr, nullptr);

  headln<<<128, b256, 0, stream>>>(QKVG, 2048);

  copyf<<<12, b256, 0, stream>>>(x_res, out_x, N_TOK * 3);

  build_W_mfma<<<4096, b256, 0, stream>>>(
      QKVG, QKVG + 512, 2048, x_res, bins, posw, wdl, eps, mask, Wb);
  build_vxt<<<dim3(H_HEADS, N_TOK / 64), b256, 0, stream>>>(QKVG, x_res, Vxt);

  sink_init<<<64, b256, 0, stream>>>(mu, nu, lv0, lmu, lnu, vtilde);

  // iteration 0: row uses warm-start vtilde; col -> partials
  sink_row<<<1024, b256, 0, stream>>>(Wb, vtilde, lmu, out_lu, utilde, eps);
  sink_colp<<<1024, b256, 0, stream>>>(Wb, utilde, part);
  // iterations 1..19
  for (int it = 1; it < 20; ++it) {
    sink_row2<<<1024, b256, 0, stream>>>(Wb, part, lnu, lmu, out_lu, utilde, eps);
    sink_colp<<<1024, b256, 0, stream>>>(Wb, utilde, part);
  }
  sink_fin<<<H_HEADS, b256, 0, stream>>>(part, lnu, out_lv, vtilde, eps);

  finalize_mfma<<<256, b256, 0, stream>>>(
      Wb, vtilde, Vxt, QKVG + 1536, 2048, x_res, mask, o_b, out_x, gamma);

  gemm_mfma64<<<dim3(8, 16), b256, 0, stream>>>(o_b, wob, h_mid,
                                                N_TOK, D_MODEL, D_MODEL, h_in, mask);

  ln_rows<<<N_TOK, b256, 0, stream>>>(h_mid, lnfw, lnfb, h2_b);

  gemm_mfma<<<dim3(32, 8), b256, 0, stream>>>(h2_b, wFFb, ffab,
                                              N_TOK, D_MODEL, 4096, nullptr, nullptr);
  silu_mul_bf<<<(N_TOK * DFF) / 256, b256, 0, stream>>>(ffab, ff_b, N_TOK * DFF);

  gemm_mfma64<<<dim3(8, 16), b256, 0, stream>>>(ff_b, w2b, out_h,
                                                N_TOK, DFF, D_MODEL, h_mid, mask);
}